// Round 2
// baseline (229.494 us; speedup 1.0000x reference)
//
#include <hip/hip_runtime.h>
#include <hip/hip_bf16.h>
#include <math.h>

// Problem constants
#define B_ROWS 8192
#define N_PTS  16384
#define D_DIM  256

// GEMM tiling
#define BM 128
#define BN 128
#define BK 32
#define KSTEPS (D_DIM / BK)       // 8
#define NSPLIT 32
#define CHUNK  (N_PTS / NSPLIT)   // 512
#define NTILES (CHUNK / BN)       // 4

// Folded constants
#define SCALE_F 144.26950408889634f   // 100 * log2(e)
#define LN2_F   0.6931471805599453f
#define LOG2E_F 1.4426950408889634f
#define GN_F    354.2135193f          // -(256/2) * ln(2*pi*0.01)

typedef __attribute__((ext_vector_type(8))) __bf16 bf16x8;
typedef __attribute__((ext_vector_type(4))) __bf16 bf16x4;
typedef __attribute__((ext_vector_type(4))) float  f32x4;

__device__ __forceinline__ float fexp2(float x) {
#if __has_builtin(__builtin_amdgcn_exp2f)
    return __builtin_amdgcn_exp2f(x);
#else
    return exp2f(x);
#endif
}

__device__ __forceinline__ void async_load16(const void* g, void* l) {
    __builtin_amdgcn_global_load_lds(
        (const __attribute__((address_space(1))) void*)g,
        (__attribute__((address_space(3))) void*)l,
        16, 0, 0);
}

// ---- merged prep: convert both matrices to bf16, compute row/col consts ----
// one 64-lane wave per row, float4 loads, pure-shuffle reduction
__global__ void prep_rows(const float* __restrict__ x, const float* __restrict__ X,
                          const float* __restrict__ W,
                          __bf16* __restrict__ xb, __bf16* __restrict__ Xb,
                          float* __restrict__ rc, float* __restrict__ c2)
{
    const int gw = blockIdx.x * 4 + (threadIdx.x >> 6);   // global wave = row id
    const int l  = threadIdx.x & 63;
    const bool isX = (gw >= B_ROWS);
    const int  r   = isX ? (gw - B_ROWS) : gw;
    const float* src = isX ? X : x;
    const float4 v = ((const float4*)(src + (size_t)r * D_DIM))[l];
    bf16x4 o;
    o[0] = (__bf16)v.x; o[1] = (__bf16)v.y; o[2] = (__bf16)v.z; o[3] = (__bf16)v.w;
    __bf16* dst = isX ? Xb : xb;
    *(bf16x4*)(dst + (size_t)r * D_DIM + l * 4) = o;
    float s = v.x * v.x + v.y * v.y + v.z * v.z + v.w * v.w;
    #pragma unroll
    for (int off = 32; off > 0; off >>= 1) s += __shfl_xor(s, off);
    if (l == 0) {
        if (isX) c2[r] = (W[r] - 50.0f * s) * LOG2E_F;
        else     rc[r] = GN_F - 50.0f * s;
    }
}

// ---- lseW = logsumexp(W), one 1024-thread block ----
__global__ void prep_w_kernel(const float* __restrict__ W, float* __restrict__ lsew)
{
    __shared__ float sm[16];
    __shared__ float bc;
    const int t = threadIdx.x;
    float v[16];
    #pragma unroll
    for (int i = 0; i < 16; ++i) v[i] = W[t + i * 1024];
    float m = v[0];
    #pragma unroll
    for (int i = 1; i < 16; ++i) m = fmaxf(m, v[i]);
    #pragma unroll
    for (int off = 32; off > 0; off >>= 1) m = fmaxf(m, __shfl_xor(m, off));
    if ((t & 63) == 0) sm[t >> 6] = m;
    __syncthreads();
    if (t == 0) {
        float M = sm[0];
        for (int i = 1; i < 16; ++i) M = fmaxf(M, sm[i]);
        bc = M;
    }
    __syncthreads();
    const float M = bc;
    float s = 0.f;
    #pragma unroll
    for (int i = 0; i < 16; ++i) s += __expf(v[i] - M);
    #pragma unroll
    for (int off = 32; off > 0; off >>= 1) s += __shfl_xor(s, off);
    if ((t & 63) == 0) sm[t >> 6] = s;
    __syncthreads();
    if (t == 0) {
        float S = 0.f;
        for (int i = 0; i < 16; ++i) S += sm[i];
        lsew[0] = M + __logf(S);
    }
}

// ---- main: dbuf-LDS bf16 MFMA GEMM + fused online log2-sum-exp ----
// LDS layout per buffer: 16B chunks, chunk c holds row=c>>2, k-chunk (c&3)^((row>>2)&3)
// (XOR swizzle kills the 8-way b128 bank conflicts; global side stays 64B-coalesced)
__global__ __launch_bounds__(256, 3) void kde_gemm(
    const __bf16* __restrict__ xb, const __bf16* __restrict__ Xb,
    const float* __restrict__ c2, float* __restrict__ pm, float* __restrict__ ps)
{
    __shared__ __align__(16) __bf16 As[2][BM * BK];   // 2 x 8 KB
    __shared__ __align__(16) __bf16 Bs[2][BN * BK];   // 2 x 8 KB
    __shared__ float redM[2][BM];
    __shared__ float redS[2][BM];

    const int tid  = threadIdx.x;
    const int lane = tid & 63;
    const int w    = tid >> 6;
    const int wy   = w >> 1;
    const int wx   = w & 1;
    const int l15  = lane & 15;
    const int quad = lane >> 4;

    const int b0    = blockIdx.x * BM;
    const int chunk = blockIdx.y;
    const int nbase = chunk * CHUNK;

    // staging: chunk c = a*256 + tid; row = c>>2; fetched k-chunk = (tid&3)^((tid>>4)&3)
    const int kcs  = (tid & 3) ^ ((tid >> 4) & 3);
    const int srow = tid >> 2;                     // + a*64
    const __bf16* aptr0 = xb + (size_t)(b0 + srow) * D_DIM + kcs * 8;
    const __bf16* aptr1 = aptr0 + (size_t)64 * D_DIM;
    const __bf16* bp0   = Xb + (size_t)(nbase + srow) * D_DIM + kcs * 8;
    const __bf16* bp1   = bp0 + (size_t)64 * D_DIM;
    const int ldsA0 = (0 * 256 + w * 64) * 8;      // wave-uniform LDS element bases
    const int ldsA1 = (1 * 256 + w * 64) * 8;

    // fragment read addresses (swizzled): elem = (row*4 + (quad^swz))*8 + i*512
    const int swz = (l15 >> 2) & 3;
    const int caA = ((wy * 64 + l15) * 4 + (quad ^ swz)) * 8;
    const int caB = ((wx * 64 + l15) * 4 + (quad ^ swz)) * 8;

    // per-lane online LSE state (rows: wy*64 + i*16 + quad*4 + r)
    float m_[4][4], s_[4][4];
    #pragma unroll
    for (int i = 0; i < 4; ++i)
        #pragma unroll
        for (int r = 0; r < 4; ++r) { m_[i][r] = -INFINITY; s_[i][r] = 0.0f; }

#define STAGE(buf, koff, BQ0, BQ1) do {                              \
        async_load16(aptr0 + (koff), &As[buf][ldsA0]);               \
        async_load16(aptr1 + (koff), &As[buf][ldsA1]);               \
        async_load16((BQ0) + (koff), &Bs[buf][ldsA0]);               \
        async_load16((BQ1) + (koff), &Bs[buf][ldsA1]);               \
    } while (0)

    STAGE(0, 0, bp0, bp1);   // prologue: kt=0 -> buf 0

    for (int nt = 0; nt < NTILES; ++nt) {
        const int n0 = nbase + nt * BN;
        float c2v[4];
        #pragma unroll
        for (int j = 0; j < 4; ++j)
            c2v[j] = c2[n0 + wx * 64 + j * 16 + l15];

        f32x4 acc[4][4];
        #pragma unroll
        for (int i = 0; i < 4; ++i)
            #pragma unroll
            for (int j = 0; j < 4; ++j) {
                f32x4 z = {0.f, 0.f, 0.f, 0.f};
                acc[i][j] = z;
            }

        #pragma unroll
        for (int kt = 0; kt < KSTEPS; ++kt) {
            __syncthreads();   // buf(kt&1) staged+visible; buf((kt+1)&1) readers done
            if (kt < KSTEPS - 1) {
                STAGE((kt + 1) & 1, (kt + 1) * BK, bp0, bp1);
            } else if (nt < NTILES - 1) {
                // KSTEPS even -> next ntile's kt=0 lands back in buf 0
                STAGE(0, 0, bp0 + (size_t)BN * D_DIM, bp1 + (size_t)BN * D_DIM);
            }
            const __bf16* Ab = &As[kt & 1][0];
            const __bf16* Bb = &Bs[kt & 1][0];
            bf16x8 af[4], bfr[4];
            #pragma unroll
            for (int i = 0; i < 4; ++i) af[i]  = *(const bf16x8*)&Ab[caA + i * 512];
            #pragma unroll
            for (int j = 0; j < 4; ++j) bfr[j] = *(const bf16x8*)&Bb[caB + j * 512];
            #pragma unroll
            for (int i = 0; i < 4; ++i)
                #pragma unroll
                for (int j = 0; j < 4; ++j)
                    acc[i][j] = __builtin_amdgcn_mfma_f32_16x16x32_bf16(af[i], bfr[j], acc[i][j], 0, 0, 0);
        }
        bp0 += (size_t)BN * D_DIM;
        bp1 += (size_t)BN * D_DIM;

        // fused epilogue (overlaps the already-issued next-ntile staging loads)
        #pragma unroll
        for (int i = 0; i < 4; ++i) {
            #pragma unroll
            for (int r = 0; r < 4; ++r) {
                float v0 = fmaf(SCALE_F, acc[i][0][r], c2v[0]);
                float v1 = fmaf(SCALE_F, acc[i][1][r], c2v[1]);
                float v2 = fmaf(SCALE_F, acc[i][2][r], c2v[2]);
                float v3 = fmaf(SCALE_F, acc[i][3][r], c2v[3]);
                float tm = fmaxf(fmaxf(v0, v1), fmaxf(v2, v3));
                float om = m_[i][r];
                float nm = fmaxf(om, tm);
                float e  = fexp2(v0 - nm) + fexp2(v1 - nm) + fexp2(v2 - nm) + fexp2(v3 - nm);
                s_[i][r] = fmaf(s_[i][r], fexp2(om - nm), e);
                m_[i][r] = nm;
            }
        }
    }
#undef STAGE

    // reduce (m,s) across the 16 lanes sharing each row, then across wx waves
    #pragma unroll
    for (int i = 0; i < 4; ++i) {
        #pragma unroll
        for (int r = 0; r < 4; ++r) {
            float mm = m_[i][r], ss = s_[i][r];
            #pragma unroll
            for (int off = 1; off < 16; off <<= 1) {
                float om = __shfl_xor(mm, off);
                float os = __shfl_xor(ss, off);
                float nm = fmaxf(mm, om);
                ss = ss * fexp2(mm - nm) + os * fexp2(om - nm);
                mm = nm;
            }
            if (l15 == 0) {
                int row = wy * 64 + i * 16 + quad * 4 + r;
                redM[wx][row] = mm;
                redS[wx][row] = ss;
            }
        }
    }
    __syncthreads();
    if (tid < BM) {
        float m0 = redM[0][tid], m1 = redM[1][tid];
        float s0 = redS[0][tid], s1 = redS[1][tid];
        float M = fmaxf(m0, m1);
        float S = s0 * fexp2(m0 - M) + s1 * fexp2(m1 - M);
        pm[(size_t)(b0 + tid) * NSPLIT + chunk] = M;
        ps[(size_t)(b0 + tid) * NSPLIT + chunk] = S;
    }
}

// ---- combine partial (m,s) across N-chunks ----
__global__ void kde_combine(const float* __restrict__ pm, const float* __restrict__ ps,
                            const float* __restrict__ rc, const float* __restrict__ lsew,
                            float* __restrict__ out)
{
    int b = blockIdx.x * blockDim.x + threadIdx.x;
    if (b >= B_ROWS) return;
    float M = -INFINITY;
    #pragma unroll
    for (int c = 0; c < NSPLIT; ++c) M = fmaxf(M, pm[(size_t)b * NSPLIT + c]);
    float S = 0.f;
    #pragma unroll
    for (int c = 0; c < NSPLIT; ++c)
        S += ps[(size_t)b * NSPLIT + c] * fexp2(pm[(size_t)b * NSPLIT + c] - M);
    out[b] = (M + log2f(S)) * LN2_F + rc[b] - lsew[0];
}

extern "C" void kernel_launch(void* const* d_in, const int* in_sizes, int n_in,
                              void* d_out, int out_size, void* d_ws, size_t ws_size,
                              hipStream_t stream)
{
    const float* x = (const float*)d_in[0];
    const float* X = (const float*)d_in[1];
    const float* W = (const float*)d_in[2];
    float* out = (float*)d_out;

    char* ws = (char*)d_ws;
    size_t off = 0;
    __bf16* xb = (__bf16*)(ws + off); off += (size_t)B_ROWS * D_DIM * 2;   // 4 MB
    __bf16* Xb = (__bf16*)(ws + off); off += (size_t)N_PTS  * D_DIM * 2;   // 8 MB
    float* rc   = (float*)(ws + off); off += (size_t)B_ROWS * 4;
    float* c2   = (float*)(ws + off); off += (size_t)N_PTS * 4;
    float* lsew = (float*)(ws + off); off += 256;
    float* pm   = (float*)(ws + off); off += (size_t)B_ROWS * NSPLIT * 4;  // 1 MB
    float* ps   = (float*)(ws + off); off += (size_t)B_ROWS * NSPLIT * 4;  // 1 MB

    prep_rows<<<(B_ROWS + N_PTS) / 4, 256, 0, stream>>>(x, X, W, xb, Xb, rc, c2);
    prep_w_kernel<<<1, 1024, 0, stream>>>(W, lsew);
    kde_gemm<<<dim3(B_ROWS / BM, NSPLIT), 256, 0, stream>>>(xb, Xb, c2, pm, ps);
    kde_combine<<<B_ROWS / 256, 256, 0, stream>>>(pm, ps, rc, lsew, out);
}